// Round 2
// baseline (61714.886 us; speedup 1.0000x reference)
//
#include <hip/hip_runtime.h>
#include <math.h>

// Problem constants
constexpr int kB = 256;
constexpr int kT = 200;
constexpr int kD = 512;
constexpr int kU = 1024;
constexpr int kG = 4096;   // 4*U

// ---------------------------------------------------------------------------
// Fused two-segment tiled fp32 GEMM for one LSTM step:
//   C[M,N] = A1[M,K1] @ Wa[K1,N] + A2[M,K2] @ Wb[K2,N] + bias[N]
// If GATHER, A1 rows come from an embedding table: row m uses
//   A1 + gidx[(row0+m)*gstride] * K1.
// Block: 256 threads. BM=32, BN=64, BK=16, TM=2, TN=4 -> 16x16 thread grid.
// ---------------------------------------------------------------------------
template <int BM, int BN, int BK, int TM, int TN, bool GATHER>
__global__ __launch_bounds__(256)
void step_gemm(const float* __restrict__ A1, const int* __restrict__ gidx, int gstride,
               const float* __restrict__ Wa, int K1,
               const float* __restrict__ A2,
               const float* __restrict__ Wb, int K2,
               const float* __restrict__ bias, float* __restrict__ C, int N)
{
    __shared__ float As[BK][BM + 1];
    __shared__ float Bs[BK][BN + 1];

    const int tid  = threadIdx.x;
    const int row0 = blockIdx.y * BM;
    const int col0 = blockIdx.x * BN;
    const int tnx  = BN / TN;            // threads along N
    const int tx   = tid % tnx;
    const int ty   = tid / tnx;

    float acc[TM][TN];
#pragma unroll
    for (int i = 0; i < TM; i++)
#pragma unroll
        for (int j = 0; j < TN; j++) acc[i][j] = 0.f;

#pragma unroll 1
    for (int seg = 0; seg < 2; seg++) {
        const float* A = (seg == 0) ? A1 : A2;
        const float* W = (seg == 0) ? Wa : Wb;
        const int    K = (seg == 0) ? K1 : K2;
        const bool   gath = GATHER && (seg == 0);

        for (int k0 = 0; k0 < K; k0 += BK) {
            // Load A tile (BM x BK)
#pragma unroll
            for (int i = 0; i < (BM * BK) / 256; i++) {
                int idx = tid + i * 256;
                int m = idx / BK, k = idx % BK;
                const float* arow = gath
                    ? (A + (long)gidx[(long)(row0 + m) * gstride] * K)
                    : (A + (long)(row0 + m) * K);
                As[k][m] = arow[k0 + k];
            }
            // Load W tile (BK x BN), coalesced along N
#pragma unroll
            for (int i = 0; i < (BK * BN) / 256; i++) {
                int idx = tid + i * 256;
                int k = idx / BN, n = idx % BN;
                Bs[k][n] = W[(long)(k0 + k) * N + col0 + n];
            }
            __syncthreads();

#pragma unroll
            for (int k = 0; k < BK; k++) {
                float a[TM], bv[TN];
#pragma unroll
                for (int i = 0; i < TM; i++) a[i] = As[k][ty * TM + i];
#pragma unroll
                for (int j = 0; j < TN; j++) bv[j] = Bs[k][tx * TN + j];
#pragma unroll
                for (int i = 0; i < TM; i++)
#pragma unroll
                    for (int j = 0; j < TN; j++) acc[i][j] += a[i] * bv[j];
            }
            __syncthreads();
        }
    }

#pragma unroll
    for (int i = 0; i < TM; i++) {
        int m = row0 + ty * TM + i;
#pragma unroll
        for (int j = 0; j < TN; j++) {
            int n = col0 + tx * TN + j;
            C[(long)m * N + n] = acc[i][j] + bias[n];
        }
    }
}

// ---------------------------------------------------------------------------
// LSTM gate pointwise: z[B,4U] (Keras order i,f,g,o), updates c,h in place.
// ---------------------------------------------------------------------------
__global__ __launch_bounds__(256)
void lstm_gates(const float* __restrict__ z, float* __restrict__ c,
                float* __restrict__ h)
{
    int idx = blockIdx.x * blockDim.x + threadIdx.x;   // [0, B*U)
    int b = idx / kU, j = idx % kU;
    const float* zr = z + (long)b * kG;
    float zi = zr[j], zf = zr[kU + j], zg = zr[2 * kU + j], zo = zr[3 * kU + j];
    float i_ = 1.f / (1.f + expf(-zi));
    float f_ = 1.f / (1.f + expf(-zf));
    float o_ = 1.f / (1.f + expf(-zo));
    float g_ = tanhf(zg);
    float cn = f_ * c[idx] + i_ * g_;
    float hn = o_ * tanhf(cn);
    c[idx] = cn;
    h[idx] = hn;
}

__global__ __launch_bounds__(256)
void zero4(float* __restrict__ a, float* __restrict__ b,
           float* __restrict__ c, float* __restrict__ d)
{
    int i = blockIdx.x * blockDim.x + threadIdx.x;
    a[i] = 0.f; b[i] = 0.f; c[i] = 0.f; d[i] = 0.f;
}

// ---------------------------------------------------------------------------
// out[b] = sigmoid(h[b,:] . Wfc + bfc)
// ---------------------------------------------------------------------------
__global__ __launch_bounds__(256)
void fc_sigmoid(const float* __restrict__ h, const float* __restrict__ Wfc,
                const float* __restrict__ bfc, float* __restrict__ out)
{
    int b = blockIdx.x;
    int tid = threadIdx.x;
    float s = 0.f;
    for (int j = tid; j < kU; j += 256) s += h[(long)b * kU + j] * Wfc[j];
    __shared__ float red[4];
    for (int off = 32; off > 0; off >>= 1) s += __shfl_down(s, off, 64);
    if ((tid & 63) == 0) red[tid >> 6] = s;
    __syncthreads();
    if (tid == 0) {
        float t = red[0] + red[1] + red[2] + red[3] + bfc[0];
        out[b] = 1.f / (1.f + expf(-t));
    }
}

extern "C" void kernel_launch(void* const* d_in, const int* in_sizes, int n_in,
                              void* d_out, int out_size, void* d_ws, size_t ws_size,
                              hipStream_t stream)
{
    (void)in_sizes; (void)n_in; (void)out_size; (void)ws_size;

    const int*   tokens = (const int*)d_in[0];
    const float* emb    = (const float*)d_in[1];
    const float* W1     = (const float*)d_in[2];
    const float* U1     = (const float*)d_in[3];
    const float* b1     = (const float*)d_in[4];
    const float* W2     = (const float*)d_in[5];
    const float* U2     = (const float*)d_in[6];
    const float* b2     = (const float*)d_in[7];
    const float* Wfc    = (const float*)d_in[8];
    const float* bfc    = (const float*)d_in[9];
    float* out = (float*)d_out;

    // Workspace layout (floats). Total ~12 MB.
    float* ws = (float*)d_ws;
    float* z1 = ws;                       // [B, 4U] = 1,048,576
    float* z2 = z1 + (size_t)kB * kG;     // [B, 4U]
    float* h1 = z2 + (size_t)kB * kG;     // [B, U]  =   262,144
    float* c1 = h1 + (size_t)kB * kU;
    float* h2 = c1 + (size_t)kB * kU;
    float* c2 = h2 + (size_t)kB * kU;

    dim3 blk(256);
    dim3 grid(kG / 64, kB / 32);          // 64 x 8 = 512 blocks

    zero4<<<(kB * kU) / 256, blk, 0, stream>>>(h1, c1, h2, c2);

    for (int t = 0; t < kT; t++) {
        // Layer 1: z1 = emb[tokens[:,t]] @ W1 + h1 @ U1 + b1
        step_gemm<32, 64, 16, 2, 4, true><<<grid, blk, 0, stream>>>(
            emb, tokens + t, kT, W1, kD, h1, U1, kU, b1, z1, kG);
        lstm_gates<<<(kB * kU) / 256, blk, 0, stream>>>(z1, c1, h1);

        // Layer 2: z2 = h1 @ W2 + h2 @ U2 + b2
        step_gemm<32, 64, 16, 2, 4, false><<<grid, blk, 0, stream>>>(
            h1, nullptr, 0, W2, kU, h2, U2, kU, b2, z2, kG);
        lstm_gates<<<(kB * kU) / 256, blk, 0, stream>>>(z2, c2, h2);
    }

    // FC head
    fc_sigmoid<<<kB, blk, 0, stream>>>(h2, Wfc, bfc, out);
}

// Round 3
// 9491.216 us; speedup vs baseline: 6.5023x; 6.5023x over previous
//
#include <hip/hip_runtime.h>
#include <math.h>

constexpr int kB = 256;
constexpr int kT = 200;
constexpr int kD = 512;
constexpr int kU = 1024;
constexpr int kG = 4096;   // 4*U

typedef short frag8 __attribute__((ext_vector_type(8)));     // 8 bf16 (4 VGPRs)
typedef float floatx4 __attribute__((ext_vector_type(4)));   // MFMA C/D frag
typedef unsigned short ushort_t;

__device__ __forceinline__ ushort_t f2bf(float f) {
    union { float f; unsigned int u; } v; v.f = f;
    unsigned int r = v.u + 0x7fffu + ((v.u >> 16) & 1u);   // RNE
    return (ushort_t)(r >> 16);
}
__device__ __forceinline__ float bf2f(ushort_t h) {
    union { unsigned int u; float f; } v; v.u = ((unsigned int)h) << 16;
    return v.f;
}

// ---------------------------------------------------------------------------
// Repack [W (K1 rows); Uw (K-K1 rows)] fp32 [*,4096] -> bf16 fragment order.
// Gate-interleaved columns: n_new = 4*j + g  <->  n_old = g*1024 + j.
// Packed: out[((nb*nkb + kb)*4 + ng)*512 + (quad*16 + nl)*8 + e]
//   = bf16(src[k = kb*32 + quad*8 + e][n_old]),  n_new = nb*64 + ng*16 + nl.
// One block per (kb, nb): coalesced reads, LDS transpose, coalesced writes.
// ---------------------------------------------------------------------------
__global__ __launch_bounds__(256)
void repack_weights(const float* __restrict__ W, const float* __restrict__ Uw,
                    int K1, int K, ushort_t* __restrict__ out)
{
    const int nkb = K >> 5;
    const int kb = blockIdx.x % nkb;
    const int nb = blockIdx.x / nkb;
    __shared__ ushort_t tile[2048];
    const int tid = threadIdx.x;
#pragma unroll
    for (int i = 0; i < 8; i++) {
        int idx  = tid + (i << 8);         // 0..2047
        int kl   = idx >> 6;               // 0..31
        int lcol = idx & 63;               // 0..63
        int g  = lcol >> 4;
        int jl = lcol & 15;
        int k  = (kb << 5) + kl;
        int n_old = (g << 10) + (nb << 4) + jl;
        float v = (k < K1) ? W[(long)k * kG + n_old]
                           : Uw[(long)(k - K1) * kG + n_old];
        int n_new_l = (jl << 2) + g;       // local packed column
        int ng = n_new_l >> 4, nl = n_new_l & 15;
        int quad = kl >> 3, e = kl & 7;
        tile[ng * 512 + (quad * 16 + nl) * 8 + e] = f2bf(v);
    }
    __syncthreads();
    long base = ((long)(nb * nkb + kb)) * 2048;
    *(frag8*)&out[base + tid * 8] = *(frag8*)&tile[tid * 8];
}

__global__ __launch_bounds__(256)
void repack_bias(const float* __restrict__ b1, const float* __restrict__ b2,
                 float* __restrict__ o1, float* __restrict__ o2)
{
    int n = blockIdx.x * blockDim.x + threadIdx.x;   // 0..4095
    int n_old = ((n & 3) << 10) + (n >> 2);
    o1[n] = b1[n_old];
    o2[n] = b2[n_old];
}

// ---------------------------------------------------------------------------
// Fused LSTM step: z = [A1 | A2] @ Wp + bias (MFMA bf16), then gates,
// updating c (fp32) and writing h (bf16). Block = 64 rows x 64 packed cols
// (= 16 j's x 4 gates). 4 waves, each 16 rows x 64 cols (4 C frags).
// B frags load straight from global (packed, lane-contiguous 16B).
// A staged via double-buffered LDS (stride 40 bf16: 16B-aligned, 2-way free).
// ---------------------------------------------------------------------------
template<int K, int K1, bool GATHER>
__device__ __forceinline__ void lstm_block_core(
    short (*As)[64 * 40], float* zs,
    const ushort_t* __restrict__ A1,    // bf16 [256][1024] (when !GATHER)
    const float*    __restrict__ embF,  // fp32 [V][512]    (when GATHER)
    const int*      __restrict__ tokens, int tstep,
    const ushort_t* __restrict__ A2,    // bf16 [256][1024]
    const ushort_t* __restrict__ Wp,    // packed bf16 [K/32][...]
    const float*    __restrict__ biasP, // fp32 [4096] interleaved
    float* __restrict__ cSt, ushort_t* __restrict__ hOut)
{
    constexpr int NKB = K >> 5;
    const int tid  = threadIdx.x;
    const int lane = tid & 63;
    const int wave = tid >> 6;
    const int nb   = blockIdx.x;        // 0..63
    const int row0 = blockIdx.y << 6;   // 0,64,128,192

    // A staging: thread -> (row sr, k-offset sk), 16B per thread
    const int sr = tid >> 2;            // 0..63
    const int sk = (tid & 3) << 3;      // 0,8,16,24
    int tok = 0;
    if (GATHER) tok = tokens[(row0 + sr) * kT + tstep];
    const float*    e_base  = GATHER ? (embF + (long)tok * kD + sk) : nullptr;
    const ushort_t* a1_base = GATHER ? nullptr : (A1 + (long)(row0 + sr) * kU + sk);
    const ushort_t* a2_base = A2 + (long)(row0 + sr) * kU + sk;

    auto stage = [&](int kb, int buf) {
        int k0 = kb << 5;
        frag8 v;
        if (k0 < K1) {
            if (GATHER) {
                const float* p = e_base + k0;
                float4 x0 = *(const float4*)(p);
                float4 x1 = *(const float4*)(p + 4);
                v[0] = (short)f2bf(x0.x); v[1] = (short)f2bf(x0.y);
                v[2] = (short)f2bf(x0.z); v[3] = (short)f2bf(x0.w);
                v[4] = (short)f2bf(x1.x); v[5] = (short)f2bf(x1.y);
                v[6] = (short)f2bf(x1.z); v[7] = (short)f2bf(x1.w);
            } else {
                v = *(const frag8*)(a1_base + k0);
            }
        } else {
            v = *(const frag8*)(a2_base + (k0 - K1));
        }
        *(frag8*)&As[buf][sr * 40 + sk] = v;
    };

    floatx4 acc0 = {0,0,0,0}, acc1 = {0,0,0,0}, acc2 = {0,0,0,0}, acc3 = {0,0,0,0};
    // A frag: lane holds A[m = lane&15][k = (lane>>4)*8 + j]
    const int arow = ((wave << 4) + (lane & 15)) * 40 + ((lane >> 4) << 3);
    const frag8* wbase = (const frag8*)Wp + (long)nb * NKB * 256 + lane;

    stage(0, 0);
    int buf = 0;
#pragma unroll 2
    for (int kb = 0; kb < NKB; kb++) {
        __syncthreads();
        frag8 af = *(frag8*)&As[buf][arow];
        const frag8* wp = wbase + kb * 256;
        frag8 b0 = wp[0];
        frag8 b1 = wp[64];
        frag8 b2 = wp[128];
        frag8 b3 = wp[192];
        if (kb + 1 < NKB) stage(kb + 1, buf ^ 1);
        acc0 = __builtin_amdgcn_mfma_f32_16x16x32_bf16(af, b0, acc0, 0, 0, 0);
        acc1 = __builtin_amdgcn_mfma_f32_16x16x32_bf16(af, b1, acc1, 0, 0, 0);
        acc2 = __builtin_amdgcn_mfma_f32_16x16x32_bf16(af, b2, acc2, 0, 0, 0);
        acc3 = __builtin_amdgcn_mfma_f32_16x16x32_bf16(af, b3, acc3, 0, 0, 0);
        buf ^= 1;
    }

    // C frag: row = (lane>>4)*4 + reg, col = lane&15 -> dump z tile to LDS
    {
        int zr = (wave << 4) + ((lane >> 4) << 2);
        int zc = lane & 15;
#pragma unroll
        for (int r = 0; r < 4; r++) {
            zs[(zr + r) * 68 +  0 + zc] = acc0[r];
            zs[(zr + r) * 68 + 16 + zc] = acc1[r];
            zs[(zr + r) * 68 + 32 + zc] = acc2[r];
            zs[(zr + r) * 68 + 48 + zc] = acc3[r];
        }
    }
    __syncthreads();

    // Gates: 64 rows x 16 j per block; local col = 4*jl + g (i,f,g,o)
#pragma unroll
    for (int i = 0; i < 4; i++) {
        int unit = tid + (i << 8);      // 0..1023
        int r  = unit >> 4;
        int jl = unit & 15;
        int m  = row0 + r;
        int j  = (nb << 4) + jl;
        float4 z4 = *(float4*)&zs[r * 68 + (jl << 2)];
        float4 bv = *(const float4*)&biasP[(((nb << 4) + jl) << 2)];
        float zi = z4.x + bv.x, zf = z4.y + bv.y;
        float zg = z4.z + bv.z, zo = z4.w + bv.w;
        float ig = 1.f / (1.f + __expf(-zi));
        float fg = 1.f / (1.f + __expf(-zf));
        float og = 1.f / (1.f + __expf(-zo));
        float gg = 1.f - 2.f / (__expf(2.f * zg) + 1.f);   // tanh
        long ci = (long)m * kU + j;
        float cn = fg * cSt[ci] + ig * gg;
        float tc = 1.f - 2.f / (__expf(2.f * cn) + 1.f);   // tanh
        cSt[ci] = cn;
        hOut[ci] = f2bf(og * tc);
    }
}

// grid (64, 4, 2): z=0 -> layer2 step t2, z=1 -> layer1 step t1=t2+1
__global__ __launch_bounds__(256)
void lstm_merged(int zmask,
    const ushort_t* h1_for2, const ushort_t* h2prev, const ushort_t* W2p,
    const float* b2p, float* c2, ushort_t* h2out,
    const float* emb, const int* tokens, int t1,
    const ushort_t* h1prev, const ushort_t* W1p,
    const float* b1p, float* c1, ushort_t* h1out)
{
    __shared__ __align__(16) short As[2][64 * 40];
    __shared__ __align__(16) float zs[64 * 68];
    if (blockIdx.z == 0) {
        if (!(zmask & 1)) return;
        lstm_block_core<2048, 1024, false>(As, zs, h1_for2, nullptr, nullptr, 0,
                                           h2prev, W2p, b2p, c2, h2out);
    } else {
        if (!(zmask & 2)) return;
        lstm_block_core<1536, 512, true>(As, zs, nullptr, emb, tokens, t1,
                                         h1prev, W1p, b1p, c1, h1out);
    }
}

// out[b] = sigmoid(h[b,:] . Wfc + bfc), h in bf16
__global__ __launch_bounds__(256)
void fc_sigmoid(const ushort_t* __restrict__ h, const float* __restrict__ Wfc,
                const float* __restrict__ bfc, float* __restrict__ out)
{
    int b = blockIdx.x, tid = threadIdx.x;
    float s = 0.f;
    for (int j = tid; j < kU; j += 256) s += bf2f(h[(long)b * kU + j]) * Wfc[j];
    __shared__ float red[4];
    for (int off = 32; off > 0; off >>= 1) s += __shfl_down(s, off, 64);
    if ((tid & 63) == 0) red[tid >> 6] = s;
    __syncthreads();
    if (tid == 0) {
        float t = red[0] + red[1] + red[2] + red[3] + bfc[0];
        out[b] = 1.f / (1.f + expf(-t));
    }
}

extern "C" void kernel_launch(void* const* d_in, const int* in_sizes, int n_in,
                              void* d_out, int out_size, void* d_ws, size_t ws_size,
                              hipStream_t stream)
{
    (void)in_sizes; (void)n_in; (void)out_size; (void)ws_size;

    const int*   tokens = (const int*)d_in[0];
    const float* emb    = (const float*)d_in[1];
    const float* W1     = (const float*)d_in[2];
    const float* U1     = (const float*)d_in[3];
    const float* b1     = (const float*)d_in[4];
    const float* W2     = (const float*)d_in[5];
    const float* U2     = (const float*)d_in[6];
    const float* b2     = (const float*)d_in[7];
    const float* Wfc    = (const float*)d_in[8];
    const float* bfc    = (const float*)d_in[9];
    float* out = (float*)d_out;

    // Workspace: ~33.6 MB
    ushort_t* W1p = (ushort_t*)d_ws;                       // [1536*4096] bf16
    ushort_t* W2p = W1p + (size_t)1536 * kG;               // [2048*4096] bf16
    float* b1p = (float*)(W2p + (size_t)2048 * kG);        // [4096] f32
    float* b2p = b1p + kG;                                 // [4096] f32
    float* c1  = b2p + kG;                                 // [256*1024] f32
    float* c2  = c1 + (size_t)kB * kU;
    ushort_t* hbuf = (ushort_t*)(c2 + (size_t)kB * kU);    // 4 x [256*1024] bf16
    ushort_t* h1b[2] = { hbuf, hbuf + (size_t)kB * kU };
    ushort_t* h2b[2] = { hbuf + 2 * (size_t)kB * kU, hbuf + 3 * (size_t)kB * kU };

    repack_weights<<<48 * 64, 256, 0, stream>>>(W1, U1, 512, 1536, W1p);
    repack_weights<<<64 * 64, 256, 0, stream>>>(W2, U2, 1024, 2048, W2p);
    repack_bias<<<16, 256, 0, stream>>>(b1, b2, b1p, b2p);
    // zero c1,c2 (fp32) + all h buffers (bf16): contiguous 4 MB
    hipMemsetAsync(c1, 0, (size_t)kB * kU * (2 * 4 + 4 * 2), stream);

    for (int l = 0; l <= kT; l++) {
        int t2 = l - 1, t1 = l;
        int zmask = (t2 >= 0 ? 1 : 0) | (t1 < kT ? 2 : 0);
        lstm_merged<<<dim3(64, 4, 2), 256, 0, stream>>>(zmask,
            h1b[(t2 + 1) & 1], h2b[t2 & 1], W2p, b2p, c2, h2b[(t2 + 1) & 1],
            emb, tokens, t1, h1b[t1 & 1], W1p, b1p, c1, h1b[(t1 + 1) & 1]);
    }

    fc_sigmoid<<<kB, 256, 0, stream>>>(h2b[0], Wfc, bfc, out);
}